// Round 3
// baseline (6532.780 us; speedup 1.0000x reference)
//
#include <hip/hip_runtime.h>
#include <hip/hip_bf16.h>

#define B_ 256
#define T_ 256
#define I_ 512
#define H_ 1024
#define CH 8          // chunk length (timesteps)
#define NCH 32        // number of chunks (T_/CH)

typedef _Float16 half8 __attribute__((ext_vector_type(8)));
typedef float floatx4 __attribute__((ext_vector_type(4)));

__device__ __forceinline__ float fsig(float x) {
  return 1.f / (1.f + __expf(-x));
}
__device__ __forceinline__ float ftanh(float x) {
  return 1.f - 2.f / (__expf(2.f * x) + 1.f);
}

// Permuted gate-row order: n' -> orig row g*H + h, with g=(n'&63)>>4, h=(n'>>6)*16+(n'&15).
// Every 64-column slice = 16 h-units x 4 gates (i,f,g,o); the 4 gates of unit
// (lane&15) land in acc[m][0..3][r] of the SAME lane -> register-local cell update.

// ---- prep: permute + convert weights to f16, layout [4096][K] ----
__global__ __launch_bounds__(256) void prep_w(
    _Float16* __restrict__ dst, const float* __restrict__ src, int K) {
  const int np = blockIdx.y;
  const int k = blockIdx.x * 256 + threadIdx.x;
  const int cc = np & 63, g = cc >> 4, j = cc & 15;
  const int orig = g * H_ + (np >> 6) * 16 + j;
  dst[(size_t)np * K + k] = (_Float16)src[(size_t)orig * K + k];
}

__global__ __launch_bounds__(256) void prep_bias(
    float* __restrict__ bs0, float* __restrict__ bs1,
    const float* __restrict__ bih0, const float* __restrict__ bhh0,
    const float* __restrict__ bih1, const float* __restrict__ bhh1) {
  const int np = blockIdx.x * 256 + threadIdx.x;   // grid 16
  const int cc = np & 63, g = cc >> 4, j = cc & 15;
  const int orig = g * H_ + (np >> 6) * 16 + j;
  bs0[np] = bih0[orig] + bhh0[orig];
  bs1[np] = bih1[orig] + bhh1[orig];
}

__global__ __launch_bounds__(256) void prep_state(
    const float* __restrict__ init, _Float16* __restrict__ h1s,
    _Float16* __restrict__ h2s, float* __restrict__ c0, float* __restrict__ c1) {
  const int idx = blockIdx.x * 256 + threadIdx.x;   // grid B_*H_/256
  const float v = init[idx];
  h1s[B_ * H_ + idx] = (_Float16)v;   // parity slot 1 (t=0 reads slot 1)
  h2s[B_ * H_ + idx] = (_Float16)v;
  c0[idx] = 0.f;
  c1[idx] = 0.f;
}

// ---- batched xg GEMM: out[i*256+b][4096] (f16, permuted cols, bias added) ----
// AMODE 0: A = ctx fp32, row r -> ctx[(b*T + tbase + i)*I_], KK=512
// AMODE 1: A = h1chunk f16 contiguous rows, KK=1024
template<int KK, int AMODE>
__global__ __launch_bounds__(256, 2) void gemm_xg(
    const void* __restrict__ Ap, const _Float16* __restrict__ Bw,
    const float* __restrict__ bias, _Float16* __restrict__ out, int tbase) {
  constexpr int NST = KK / 64;
  __shared__ _Float16 As[2][128 * 72];
  __shared__ _Float16 Bs[2][128 * 72];
  const int tid = threadIdx.x;
  const int row0 = blockIdx.x * 128, col0 = blockIdx.y * 128;
  const int sr = tid >> 1, sc = (tid & 1) * 32;    // staging row / half-col base
  const int gr = row0 + sr;
  const size_t arow = (AMODE == 0)
      ? ((size_t)(gr & 255) * T_ + (size_t)tbase + (gr >> 8)) * I_
      : (size_t)gr * KK;
  const float*    af32 = (const float*)Ap + arow + sc;
  const _Float16* af16 = (const _Float16*)Ap + arow + sc;
  const _Float16* bsrc = Bw + (size_t)(col0 + sr) * KK + sc;

  const int w = tid >> 6, lane = tid & 63;
  const int wm = (w >> 1) * 64, wn = (w & 1) * 64;
  const int l15 = lane & 15, kg = (lane >> 4) * 8;
  floatx4 acc[4][4] = {};
  half8 ar[4], br[4];

  auto load_stage = [&](int ki) {
    const int k = ki * 64;
    #pragma unroll
    for (int c = 0; c < 4; ++c) {
      if (AMODE == 0) {
        float4 f0 = *(const float4*)(af32 + k + c * 8);
        float4 f1 = *(const float4*)(af32 + k + c * 8 + 4);
        half8 h;
        h[0] = (_Float16)f0.x; h[1] = (_Float16)f0.y;
        h[2] = (_Float16)f0.z; h[3] = (_Float16)f0.w;
        h[4] = (_Float16)f1.x; h[5] = (_Float16)f1.y;
        h[6] = (_Float16)f1.z; h[7] = (_Float16)f1.w;
        ar[c] = h;
      } else {
        ar[c] = *(const half8*)(af16 + k + c * 8);
      }
      br[c] = *(const half8*)(bsrc + k + c * 8);
    }
  };
  auto write_stage = [&](int buf) {
    #pragma unroll
    for (int c = 0; c < 4; ++c) *(half8*)(&As[buf][sr * 72 + sc + c * 8]) = ar[c];
    #pragma unroll
    for (int c = 0; c < 4; ++c) *(half8*)(&Bs[buf][sr * 72 + sc + c * 8]) = br[c];
  };

  load_stage(0); write_stage(0); __syncthreads();
  for (int ki = 0; ki < NST; ++ki) {
    const int cur = ki & 1;
    if (ki + 1 < NST) load_stage(ki + 1);
    #pragma unroll
    for (int ks = 0; ks < 2; ++ks) {
      half8 bf[4];
      #pragma unroll
      for (int n = 0; n < 4; ++n)
        bf[n] = *(const half8*)(&Bs[cur][(wn + 16 * n + l15) * 72 + ks * 32 + kg]);
      #pragma unroll
      for (int m = 0; m < 4; ++m) {
        half8 af = *(const half8*)(&As[cur][(wm + 16 * m + l15) * 72 + ks * 32 + kg]);
        #pragma unroll
        for (int n = 0; n < 4; ++n)
          acc[m][n] = __builtin_amdgcn_mfma_f32_16x16x32_f16(af, bf[n], acc[m][n], 0, 0, 0);
      }
    }
    if (ki + 1 < NST) write_stage(cur ^ 1);
    __syncthreads();
  }

  const int crow = (lane >> 4) * 4;
  #pragma unroll
  for (int n = 0; n < 4; ++n) {
    const int col = col0 + wn + 16 * n + l15;
    const float bv = bias[col];
    #pragma unroll
    for (int m = 0; m < 4; ++m) {
      const int rbase = row0 + wm + 16 * m + crow;
      #pragma unroll
      for (int r = 0; r < 4; ++r)
        out[(size_t)(rbase + r) * 4096 + col] = (_Float16)(acc[m][n][r] + bv);
    }
  }
}

// ---- fused recurrent step: 256 blocks. bid>>7 = layer; within layer:
//      2 row-strips of 128 batch x 64 col-blocks of 64 gate-cols. K=1024 full.
__global__ __launch_bounds__(256) void lstm_step(
    const _Float16* __restrict__ Wh0, const _Float16* __restrict__ Wh1,
    const _Float16* __restrict__ xg0, const _Float16* __restrict__ xg1,
    _Float16* __restrict__ h1s, _Float16* __restrict__ h2s,
    _Float16* __restrict__ h1chunk, float* __restrict__ c0buf,
    float* __restrict__ c1buf, float* __restrict__ hF, int t0, int t1, int ci) {
  const int bid = blockIdx.x;
  const int layer = bid >> 7;
  const int t = layer ? t1 : t0;
  if (t < 0) return;
  const int b7 = bid & 127;
  const int row0 = (b7 >> 6) * 128;    // batch-row strip (0 or 128)
  const int nb = b7 & 63;              // col-block (16 h-units)
  const int col0 = nb * 64;
  const _Float16* __restrict__ Wh = layer ? Wh1 : Wh0;
  const _Float16* __restrict__ xg = (layer ? xg1 : xg0) + (size_t)ci * 256 * 4096;
  _Float16* __restrict__ hs = layer ? h2s : h1s;
  float* __restrict__ cbuf = layer ? c1buf : c0buf;
  const int rd = (t + 1) & 1, wr = t & 1;
  const _Float16* __restrict__ hin = hs + rd * (B_ * H_);

  __shared__ _Float16 As[2][128 * 72];   // 36 KB
  __shared__ _Float16 Bs[2][64 * 72];    // 18 KB

  const int tid = threadIdx.x;
  const int srow = tid >> 3;            // 0..31
  const int spc = (tid & 7) * 8;        // 8-f16 piece within 64-k chunk
  const _Float16* asrc = hin + (size_t)(row0 + srow) * H_ + spc;
  const _Float16* bsrc = Wh + (size_t)(col0 + srow) * H_ + spc;
  half8 ar[4], br[2];

  auto load_stage = [&](int ki) {
    const int k = ki * 64;
    #pragma unroll
    for (int p = 0; p < 4; ++p) ar[p] = *(const half8*)(asrc + (size_t)(p * 32) * H_ + k);
    #pragma unroll
    for (int p = 0; p < 2; ++p) br[p] = *(const half8*)(bsrc + (size_t)(p * 32) * H_ + k);
  };
  auto write_stage = [&](int buf) {
    #pragma unroll
    for (int p = 0; p < 4; ++p) *(half8*)(&As[buf][(srow + p * 32) * 72 + spc]) = ar[p];
    #pragma unroll
    for (int p = 0; p < 2; ++p) *(half8*)(&Bs[buf][(srow + p * 32) * 72 + spc]) = br[p];
  };

  const int w = tid >> 6, lane = tid & 63;
  const int l15 = lane & 15, kg = (lane >> 4) * 8;
  const int wrow = w * 32;              // wave's 32-row slice of the 128-row strip
  floatx4 acc[2][4] = {};

  load_stage(0); write_stage(0); __syncthreads();
  for (int ki = 0; ki < 16; ++ki) {
    const int cur = ki & 1;
    if (ki < 15) load_stage(ki + 1);
    #pragma unroll
    for (int ks = 0; ks < 2; ++ks) {
      half8 bf[4];
      #pragma unroll
      for (int n = 0; n < 4; ++n)
        bf[n] = *(const half8*)(&Bs[cur][(16 * n + l15) * 72 + ks * 32 + kg]);
      #pragma unroll
      for (int m = 0; m < 2; ++m) {
        half8 af = *(const half8*)(&As[cur][(wrow + 16 * m + l15) * 72 + ks * 32 + kg]);
        #pragma unroll
        for (int n = 0; n < 4; ++n)
          acc[m][n] = __builtin_amdgcn_mfma_f32_16x16x32_f16(af, bf[n], acc[m][n], 0, 0, 0);
      }
    }
    if (ki < 15) write_stage(cur ^ 1);
    __syncthreads();
  }

  // ---- register-local cell update: lane owns h-unit l15, 8 batch rows ----
  const int hu = nb * 16 + l15;
  const int rsub = (lane >> 4) * 4;
  #pragma unroll
  for (int m = 0; m < 2; ++m) {
    #pragma unroll
    for (int r = 0; r < 4; ++r) {
      const int brow = row0 + wrow + 16 * m + rsub + r;
      const _Float16* xr = xg + (size_t)brow * 4096 + col0;
      const float gi = acc[m][0][r] + (float)xr[l15];
      const float gf = acc[m][1][r] + (float)xr[16 + l15];
      const float gg = acc[m][2][r] + (float)xr[32 + l15];
      const float go = acc[m][3][r] + (float)xr[48 + l15];
      const float si = fsig(gi);
      const float sf = fsig(gf);
      const float so = fsig(go);
      const float tg = ftanh(gg);
      const size_t cidx = (size_t)brow * H_ + hu;
      const float cn = sf * cbuf[cidx] + si * tg;
      const float hn = so * ftanh(cn);
      cbuf[cidx] = cn;
      hs[wr * (B_ * H_) + cidx] = (_Float16)hn;
      if (layer == 0)
        h1chunk[((size_t)ci * 256 + brow) * H_ + hu] = (_Float16)hn;
      else
        hF[cidx] = hn;
    }
  }
}

// ---- readout: out[b] = hF[b,:] . W_ro + b_ro ----
__global__ __launch_bounds__(256) void readout(
    const float* __restrict__ hF, const float* __restrict__ Wro,
    const float* __restrict__ bro, float* __restrict__ out) {
  const int b = blockIdx.x;
  const int tid = threadIdx.x;
  float p = 0.f;
  for (int h = tid; h < H_; h += 256) p += hF[(size_t)b * H_ + h] * Wro[h];
  #pragma unroll
  for (int off = 32; off; off >>= 1) p += __shfl_down(p, off, 64);
  __shared__ float red[4];
  if ((tid & 63) == 0) red[tid >> 6] = p;
  __syncthreads();
  if (tid == 0) out[b] = red[0] + red[1] + red[2] + red[3] + bro[0];
}

extern "C" void kernel_launch(void* const* d_in, const int* in_sizes, int n_in,
                              void* d_out, int out_size, void* d_ws, size_t ws_size,
                              hipStream_t stream) {
  const float* init_hidden = (const float*)d_in[0];
  const float* ctx   = (const float*)d_in[1];
  const float* W_ih0 = (const float*)d_in[2];
  const float* W_hh0 = (const float*)d_in[3];
  const float* b_ih0 = (const float*)d_in[4];
  const float* b_hh0 = (const float*)d_in[5];
  const float* W_ih1 = (const float*)d_in[6];
  const float* W_hh1 = (const float*)d_in[7];
  const float* b_ih1 = (const float*)d_in[8];
  const float* b_hh1 = (const float*)d_in[9];
  const float* W_ro  = (const float*)d_in[10];
  const float* b_ro  = (const float*)d_in[11];

  char* ws = (char*)d_ws;
  _Float16* W0p  = (_Float16*)(ws);                  // 4096*512*2  = 4,194,304
  _Float16* Wh0p = (_Float16*)(ws + 4194304);        // 4096*1024*2 = 8,388,608
  _Float16* W1p  = (_Float16*)(ws + 12582912);       // 8,388,608
  _Float16* Wh1p = (_Float16*)(ws + 20971520);       // 8,388,608
  float*    bs0  = (float*)(ws + 29360128);          // 16,384
  float*    bs1  = (float*)(ws + 29376512);          // 16,384
  _Float16* xg0  = (_Float16*)(ws + 29392896);       // 8*256*4096*2 = 16,777,216
  _Float16* xg1  = (_Float16*)(ws + 46170112);       // 16,777,216
  _Float16* h1c  = (_Float16*)(ws + 62947328);       // 2048*1024*2 = 4,194,304
  _Float16* h1s  = (_Float16*)(ws + 67141632);       // 1,048,576
  _Float16* h2s  = (_Float16*)(ws + 68190208);       // 1,048,576
  float*    c0   = (float*)(ws + 69238784);          // 1,048,576
  float*    c1   = (float*)(ws + 70287360);          // 1,048,576
  float*    hF   = (float*)(ws + 71335936);          // 1,048,576 -> end 72,384,512

  prep_w<<<dim3(I_ / 256, 4096), 256, 0, stream>>>(W0p, W_ih0, I_);
  prep_w<<<dim3(H_ / 256, 4096), 256, 0, stream>>>(Wh0p, W_hh0, H_);
  prep_w<<<dim3(H_ / 256, 4096), 256, 0, stream>>>(W1p, W_ih1, H_);
  prep_w<<<dim3(H_ / 256, 4096), 256, 0, stream>>>(Wh1p, W_hh1, H_);
  prep_bias<<<dim3(16), 256, 0, stream>>>(bs0, bs1, b_ih0, b_hh0, b_ih1, b_hh1);
  prep_state<<<dim3(B_ * H_ / 256), 256, 0, stream>>>(init_hidden, h1s, h2s, c0, c1);

  for (int c = 0; c <= NCH; ++c) {
    if (c < NCH)
      gemm_xg<512, 0><<<dim3(16, 32), 256, 0, stream>>>(ctx, W0p, bs0, xg0, c * CH);
    if (c >= 1)
      gemm_xg<1024, 1><<<dim3(16, 32), 256, 0, stream>>>(h1c, W1p, bs1, xg1, 0);
    for (int i = 0; i < CH; ++i) {
      const int t0 = (c < NCH) ? c * CH + i : -1;
      const int t1 = (c >= 1) ? (c - 1) * CH + i : -1;
      lstm_step<<<dim3(256), 256, 0, stream>>>(Wh0p, Wh1p, xg0, xg1, h1s, h2s,
                                               h1c, c0, c1, hF, t0, t1, i);
    }
  }
  readout<<<dim3(B_), 256, 0, stream>>>(hF, W_ro, b_ro, (float*)d_out);
}